// Round 6
// baseline (71.329 us; speedup 1.0000x reference)
//
#include <hip/hip_runtime.h>
#include <math.h>

// B=2,T=4096,N=4,DIM=2048 -> 32768 rows of 2048 f32 (256 MiB in, 768 KiB out)
// out = H_pre[32768] ++ H_post[32768] ++ H_res[B,T,4,4] (131072), f32
//
// Fusion: dot(theta, x_tilde) = rstd * sum_c (theta[c]*w[c]) * x[c]
// -> single pass over x: sum(x^2) + 6 folded dots, then tanh epilogue.
//
// Round-6 (persistent squeeze of the 46.6us round-5 kernel):
//   - grid 512 x 1024 threads = exactly 2 blocks/CU, all resident:
//     theta fill + barrier 2x per CU (was 4x), no block turnover
//   - each wave owns 2 pairs (rows gw,gw+16384 and gw+8192,gw+24576);
//     pair-B's 16 loads issue before pair-A's reduction (x regs dead there)
//     -> loads in flight across reduce/epilogue phases
//   - theta shared across the 2 rows of a pair (24 ds_read_b128/row),
//     DPP row_ror reduction (VALU) + 2 shuffles per chain (round-5 wins)
#define DIM     2048
#define NROWS   32768
#define EPS_RMS 1e-6f
#define NTH     6
#define BLK     1024
#define GRIDN   512      // 8192 waves x 2 pairs x 2 rows = 32768 rows

__device__ __forceinline__ float fast_tanh(float x) {
    // tanh(x) = 1 - 2/(exp(2x)+1); ~1e-7 rel err, exact at +/-inf
    return 1.0f - 2.0f / (__expf(2.0f * x) + 1.0f);
}

#define DOT4(t, a) ((t).x*(a).x + (t).y*(a).y + (t).z*(a).z + (t).w*(a).w)

// v += row_ror:<k>(v)  (within 16-lane DPP rows; VALU pipe, no DS traffic)
#define ROR_ADD(v, CTRL)                                                      \
    do {                                                                      \
        int _iv = __float_as_int(v);                                          \
        int _r  = __builtin_amdgcn_update_dpp(_iv, _iv, (CTRL), 0xF, 0xF, false); \
        (v) += __int_as_float(_r);                                            \
    } while (0)

// full 64-lane sum, result broadcast to all lanes
#define WAVE_SUM(v)                                                           \
    do {                                                                      \
        ROR_ADD(v, 0x121);  /* row_ror:1 */                                   \
        ROR_AD2(v)                                                            \
    } while (0)
#define ROR_AD2(v)                                                            \
        ROR_ADD(v, 0x122);  /* row_ror:2 */                                   \
        ROR_ADD(v, 0x124);  /* row_ror:4 */                                   \
        ROR_ADD(v, 0x128);  /* row_ror:8 */                                   \
        (v) += __shfl_xor((v), 16);                                           \
        (v) += __shfl_xor((v), 32);

__global__ __launch_bounds__(BLK, 4) void hcmaps_kernel(
    const float* __restrict__ x,
    const float* __restrict__ w,
    const float* __restrict__ alpha_pre_p,
    const float* __restrict__ alpha_post_p,
    const float* __restrict__ alpha_res_p,
    const float* __restrict__ theta_pre,
    const float* __restrict__ theta_post,
    const float* __restrict__ theta_res,   // [4, DIM]
    const float* __restrict__ b_pre,       // [4]
    const float* __restrict__ b_post,      // [4]
    const float* __restrict__ b_res,       // [16] = [i][n]
    float* __restrict__ out)
{
    __shared__ float s_wt[NTH * DIM];      // 48 KiB: w*theta, 6 vectors

    const int tid  = threadIdx.x;
    const int lane = tid & 63;
    const int wid  = tid >> 6;
    const int gw   = blockIdx.x * 16 + wid;      // 0..8191

    const float4* __restrict__ xf4 = (const float4*)x;

    // ---- pair A: issue ALL 16 loads up front (hide under theta fill) ----
    float4 xa0[4], xa1[4], xb0[4], xb1[4];       // rowA0 c0/c1, rowA1 c0/c1
    {
        const float4* ra = xf4 + (size_t)gw * 512;
        const float4* rb = xf4 + ((size_t)gw + 16384) * 512;
#pragma unroll
        for (int j = 0; j < 4; ++j) {
            xa0[j] = ra[j * 64 + lane];
            xb0[j] = rb[j * 64 + lane];
            xa1[j] = ra[256 + j * 64 + lane];
            xb1[j] = rb[256 + j * 64 + lane];
        }
    }

    // ---- fold w*theta into LDS (3 float4 per thread) ----
#pragma unroll
    for (int it = 0; it < 3; ++it) {
        const int q  = tid + it * BLK;           // 0..3071
        const int v  = q >> 9;                   // theta index 0..5
        const int cf = q & 511;                  // float4 col
        const float* tb = (v == 0) ? theta_pre
                        : (v == 1) ? theta_post
                                   : (theta_res + (v - 2) * DIM);
        const float4 wv = ((const float4*)w)[cf];
        const float4 t4 = ((const float4*)tb)[cf];
        ((float4*)s_wt)[q] =
            make_float4(wv.x * t4.x, wv.y * t4.y, wv.z * t4.z, wv.w * t4.w);
    }

    const float apre  = alpha_pre_p[0];
    const float apost = alpha_post_p[0];
    const float ares  = alpha_res_p[0];
    const int   n     = gw & 3;                  // same for all 4 owned rows
    const int   s     = lane & 7;                // epilogue output selector
    float bias = 0.f, alpha = 0.f;
    if (s < 6) {
        alpha = (s == 0) ? apre : (s == 1) ? apost : ares;
        bias  = (s == 0) ? b_pre[n]
              : (s == 1) ? b_post[n]
                         : b_res[(s - 2) * 4 + n];
    }

    __syncthreads();

    // ================= pair A compute =================
    float ssa = 0.f, ssb = 0.f;
    float da0 = 0.f, da1 = 0.f, da2 = 0.f, da3 = 0.f, da4 = 0.f, da5 = 0.f;
    float db0 = 0.f, db1 = 0.f, db2 = 0.f, db3 = 0.f, db4 = 0.f, db5 = 0.f;

#pragma unroll
    for (int j = 0; j < 4; ++j) {
        const float4 a = xa0[j], b = xb0[j];
        const float* tb = s_wt + j * 256 + lane * 4;
        ssa += DOT4(a, a); ssb += DOT4(b, b);
        float4 t;
        t = *(const float4*)(tb + 0 * DIM); da0 += DOT4(t, a); db0 += DOT4(t, b);
        t = *(const float4*)(tb + 1 * DIM); da1 += DOT4(t, a); db1 += DOT4(t, b);
        t = *(const float4*)(tb + 2 * DIM); da2 += DOT4(t, a); db2 += DOT4(t, b);
        t = *(const float4*)(tb + 3 * DIM); da3 += DOT4(t, a); db3 += DOT4(t, b);
        t = *(const float4*)(tb + 4 * DIM); da4 += DOT4(t, a); db4 += DOT4(t, b);
        t = *(const float4*)(tb + 5 * DIM); da5 += DOT4(t, a); db5 += DOT4(t, b);
    }
#pragma unroll
    for (int j = 0; j < 4; ++j) {
        const float4 a = xa1[j], b = xb1[j];
        const float* tb = s_wt + 1024 + j * 256 + lane * 4;
        ssa += DOT4(a, a); ssb += DOT4(b, b);
        float4 t;
        t = *(const float4*)(tb + 0 * DIM); da0 += DOT4(t, a); db0 += DOT4(t, b);
        t = *(const float4*)(tb + 1 * DIM); da1 += DOT4(t, a); db1 += DOT4(t, b);
        t = *(const float4*)(tb + 2 * DIM); da2 += DOT4(t, a); db2 += DOT4(t, b);
        t = *(const float4*)(tb + 3 * DIM); da3 += DOT4(t, a); db3 += DOT4(t, b);
        t = *(const float4*)(tb + 4 * DIM); da4 += DOT4(t, a); db4 += DOT4(t, b);
        t = *(const float4*)(tb + 5 * DIM); da5 += DOT4(t, a); db5 += DOT4(t, b);
    }

    // ---- pair B: issue all 16 loads now (x regs dead; in flight across
    //      pair-A reduction + epilogue) ----
    {
        const float4* ra = xf4 + ((size_t)gw + 8192) * 512;
        const float4* rb = xf4 + ((size_t)gw + 24576) * 512;
#pragma unroll
        for (int j = 0; j < 4; ++j) {
            xa0[j] = ra[j * 64 + lane];
            xb0[j] = rb[j * 64 + lane];
            xa1[j] = ra[256 + j * 64 + lane];
            xb1[j] = rb[256 + j * 64 + lane];
        }
    }

    // ---- pair A reduce + epilogue ----
    WAVE_SUM(ssa); WAVE_SUM(ssb);
    WAVE_SUM(da0); WAVE_SUM(da1); WAVE_SUM(da2);
    WAVE_SUM(da3); WAVE_SUM(da4); WAVE_SUM(da5);
    WAVE_SUM(db0); WAVE_SUM(db1); WAVE_SUM(db2);
    WAVE_SUM(db3); WAVE_SUM(db4); WAVE_SUM(db5);
    {
        const bool rowB = lane >= 8;
        if (s < 6 && lane < 14) {
            const float ss = rowB ? ssb : ssa;
            const float c0 = rowB ? db0 : da0;
            const float c1 = rowB ? db1 : da1;
            const float c2 = rowB ? db2 : da2;
            const float c3 = rowB ? db3 : da3;
            const float c4 = rowB ? db4 : da4;
            const float c5 = rowB ? db5 : da5;
            const float dv = (s == 0) ? c0 : (s == 1) ? c1 : (s == 2) ? c2
                           : (s == 3) ? c3 : (s == 4) ? c4 : c5;
            const int   r  = rowB ? (gw + 16384) : gw;
            const float rstd = rsqrtf(ss * (1.0f / DIM) + EPS_RMS);
            const float val  = alpha * fast_tanh(dv * rstd) + bias;
            int addr;
            if (s == 0)      addr = r;
            else if (s == 1) addr = NROWS + r;
            else             addr = 2 * NROWS + (r >> 2) * 16 + (s - 2) * 4 + n;
            out[addr] = val;
        }
    }

    // ================= pair B compute =================
    ssa = 0.f; ssb = 0.f;
    da0 = 0.f; da1 = 0.f; da2 = 0.f; da3 = 0.f; da4 = 0.f; da5 = 0.f;
    db0 = 0.f; db1 = 0.f; db2 = 0.f; db3 = 0.f; db4 = 0.f; db5 = 0.f;

#pragma unroll
    for (int j = 0; j < 4; ++j) {
        const float4 a = xa0[j], b = xb0[j];
        const float* tb = s_wt + j * 256 + lane * 4;
        ssa += DOT4(a, a); ssb += DOT4(b, b);
        float4 t;
        t = *(const float4*)(tb + 0 * DIM); da0 += DOT4(t, a); db0 += DOT4(t, b);
        t = *(const float4*)(tb + 1 * DIM); da1 += DOT4(t, a); db1 += DOT4(t, b);
        t = *(const float4*)(tb + 2 * DIM); da2 += DOT4(t, a); db2 += DOT4(t, b);
        t = *(const float4*)(tb + 3 * DIM); da3 += DOT4(t, a); db3 += DOT4(t, b);
        t = *(const float4*)(tb + 4 * DIM); da4 += DOT4(t, a); db4 += DOT4(t, b);
        t = *(const float4*)(tb + 5 * DIM); da5 += DOT4(t, a); db5 += DOT4(t, b);
    }
#pragma unroll
    for (int j = 0; j < 4; ++j) {
        const float4 a = xa1[j], b = xb1[j];
        const float* tb = s_wt + 1024 + j * 256 + lane * 4;
        ssa += DOT4(a, a); ssb += DOT4(b, b);
        float4 t;
        t = *(const float4*)(tb + 0 * DIM); da0 += DOT4(t, a); db0 += DOT4(t, b);
        t = *(const float4*)(tb + 1 * DIM); da1 += DOT4(t, a); db1 += DOT4(t, b);
        t = *(const float4*)(tb + 2 * DIM); da2 += DOT4(t, a); db2 += DOT4(t, b);
        t = *(const float4*)(tb + 3 * DIM); da3 += DOT4(t, a); db3 += DOT4(t, b);
        t = *(const float4*)(tb + 4 * DIM); da4 += DOT4(t, a); db4 += DOT4(t, b);
        t = *(const float4*)(tb + 5 * DIM); da5 += DOT4(t, a); db5 += DOT4(t, b);
    }

    // ---- pair B reduce + epilogue ----
    WAVE_SUM(ssa); WAVE_SUM(ssb);
    WAVE_SUM(da0); WAVE_SUM(da1); WAVE_SUM(da2);
    WAVE_SUM(da3); WAVE_SUM(da4); WAVE_SUM(da5);
    WAVE_SUM(db0); WAVE_SUM(db1); WAVE_SUM(db2);
    WAVE_SUM(db3); WAVE_SUM(db4); WAVE_SUM(db5);
    {
        const bool rowB = lane >= 8;
        if (s < 6 && lane < 14) {
            const float ss = rowB ? ssb : ssa;
            const float c0 = rowB ? db0 : da0;
            const float c1 = rowB ? db1 : da1;
            const float c2 = rowB ? db2 : da2;
            const float c3 = rowB ? db3 : da3;
            const float c4 = rowB ? db4 : da4;
            const float c5 = rowB ? db5 : da5;
            const float dv = (s == 0) ? c0 : (s == 1) ? c1 : (s == 2) ? c2
                           : (s == 3) ? c3 : (s == 4) ? c4 : c5;
            const int   r  = rowB ? (gw + 24576) : (gw + 8192);
            const float rstd = rsqrtf(ss * (1.0f / DIM) + EPS_RMS);
            const float val  = alpha * fast_tanh(dv * rstd) + bias;
            int addr;
            if (s == 0)      addr = r;
            else if (s == 1) addr = NROWS + r;
            else             addr = 2 * NROWS + (r >> 2) * 16 + (s - 2) * 4 + n;
            out[addr] = val;
        }
    }
}

extern "C" void kernel_launch(void* const* d_in, const int* in_sizes, int n_in,
                              void* d_out, int out_size, void* d_ws, size_t ws_size,
                              hipStream_t stream) {
    const float* x          = (const float*)d_in[0];
    const float* rms_weight = (const float*)d_in[1];
    const float* alpha_pre  = (const float*)d_in[2];
    const float* alpha_post = (const float*)d_in[3];
    const float* alpha_res  = (const float*)d_in[4];
    const float* theta_pre  = (const float*)d_in[5];
    const float* theta_post = (const float*)d_in[6];
    const float* theta_res  = (const float*)d_in[7];
    const float* b_pre      = (const float*)d_in[8];
    const float* b_post     = (const float*)d_in[9];
    const float* b_res      = (const float*)d_in[10];
    float* out = (float*)d_out;

    dim3 grid(GRIDN);
    dim3 block(BLK);
    hipLaunchKernelGGL(hcmaps_kernel, grid, block, 0, stream,
                       x, rms_weight, alpha_pre, alpha_post, alpha_res,
                       theta_pre, theta_post, theta_res,
                       b_pre, b_post, b_res, out);
}

// Round 7
// 47.748 us; speedup vs baseline: 1.4938x; 1.4938x over previous
//
#include <hip/hip_runtime.h>
#include <math.h>

// B=2,T=4096,N=4,DIM=2048 -> 32768 rows of 2048 f32 (256 MiB in, 768 KiB out)
// out = H_pre[32768] ++ H_post[32768] ++ H_res[B,T,4,4] (131072), f32
//
// Fusion: dot(theta, x_tilde) = rstd * sum_c (theta[c]*w[c]) * x[c]
// -> single pass over x: sum(x^2) + 6 folded dots, then tanh epilogue.
//
// Round-7 = round-5 structure (proven 46.6us) + v_pk_fma_f32 dot kernel.
//   Round-6 lesson: 16 live float4 of x crossed the VGPR=64 occupancy cliff
//   (waves/SIMD halve at 64/128/256) -> 71us. Keep per-wave x state at
//   8 float4; keep 1024-thread blocks, 48 KiB LDS theta, DPP reduction.
//   This round's single variable: packed 2xf32 FMA halves VALU dot work
//   (56 -> 28 FMA-instr per j-step). A/B decision: if dur unchanged,
//   memory-path-bound confirmed -> roofline.
#define DIM     2048
#define NROWS   32768
#define EPS_RMS 1e-6f
#define NTH     6
#define BLK     1024
#define GRIDN   1024     // 16384 waves; each owns rows gw and gw+16384

typedef float f32x2 __attribute__((ext_vector_type(2)));

__device__ __forceinline__ float fast_tanh(float x) {
    // tanh(x) = 1 - 2/(exp(2x)+1); ~1e-7 rel err, exact at +/-inf
    return 1.0f - 2.0f / (__expf(2.0f * x) + 1.0f);
}

__device__ __forceinline__ f32x2 mk2(float lo, float hi) {
    f32x2 r; r[0] = lo; r[1] = hi; return r;
}

// acc(f32x2) += u * v, elementwise, single VOP3P instruction
#define PKFMA(acc, u, v)                                                      \
    asm("v_pk_fma_f32 %0, %1, %2, %0" : "+v"(acc) : "v"(u), "v"(v))

// v += row_ror:<k>(v)  (within 16-lane DPP rows; VALU pipe, no DS traffic)
#define ROR_ADD(v, CTRL)                                                      \
    do {                                                                      \
        int _iv = __float_as_int(v);                                          \
        int _r  = __builtin_amdgcn_update_dpp(_iv, _iv, (CTRL), 0xF, 0xF, false); \
        (v) += __int_as_float(_r);                                            \
    } while (0)

// full 64-lane sum, result broadcast to all lanes:
// 4 DPP rotate-adds (16-lane groups) + xor16 + xor32
#define WAVE_SUM(v)                                                           \
    do {                                                                      \
        ROR_ADD(v, 0x121);  /* row_ror:1 */                                   \
        ROR_ADD(v, 0x122);  /* row_ror:2 */                                   \
        ROR_ADD(v, 0x124);  /* row_ror:4 */                                   \
        ROR_ADD(v, 0x128);  /* row_ror:8 */                                   \
        (v) += __shfl_xor((v), 16);                                           \
        (v) += __shfl_xor((v), 32);                                           \
    } while (0)

__global__ __launch_bounds__(BLK, 4) void hcmaps_kernel(
    const float* __restrict__ x,
    const float* __restrict__ w,
    const float* __restrict__ alpha_pre_p,
    const float* __restrict__ alpha_post_p,
    const float* __restrict__ alpha_res_p,
    const float* __restrict__ theta_pre,
    const float* __restrict__ theta_post,
    const float* __restrict__ theta_res,   // [4, DIM]
    const float* __restrict__ b_pre,       // [4]
    const float* __restrict__ b_post,      // [4]
    const float* __restrict__ b_res,       // [16] = [i][n]
    float* __restrict__ out)
{
    __shared__ float s_wt[NTH * DIM];      // 48 KiB: w*theta, 6 vectors

    const int tid  = threadIdx.x;
    const int lane = tid & 63;
    const int wid  = tid >> 6;
    const int gw   = blockIdx.x * 16 + wid;      // 0..16383
    const int r0   = gw;
    const int r1   = gw + 16384;

    const float4* __restrict__ xf4 = (const float4*)x;

    // ---- issue chunk-0 loads for BOTH rows first (hide under theta fill) ----
    float4 xa[4], xb[4];
    {
        const float4* ra = xf4 + (size_t)r0 * 512;
        const float4* rb = xf4 + (size_t)r1 * 512;
#pragma unroll
        for (int j = 0; j < 4; ++j) {
            xa[j] = ra[j * 64 + lane];
            xb[j] = rb[j * 64 + lane];
        }
    }

    // ---- fold w*theta into LDS (3 float4 per thread) ----
#pragma unroll
    for (int it = 0; it < 3; ++it) {
        const int q  = tid + it * BLK;           // 0..3071
        const int v  = q >> 9;                   // theta index 0..5
        const int cf = q & 511;                  // float4 col
        const float* tb = (v == 0) ? theta_pre
                        : (v == 1) ? theta_post
                                   : (theta_res + (v - 2) * DIM);
        const float4 wv = ((const float4*)w)[cf];
        const float4 t4 = ((const float4*)tb)[cf];
        ((float4*)s_wt)[q] =
            make_float4(wv.x * t4.x, wv.y * t4.y, wv.z * t4.z, wv.w * t4.w);
    }

    const float apre  = alpha_pre_p[0];
    const float apost = alpha_post_p[0];
    const float ares  = alpha_res_p[0];
    const int   n     = gw & 3;                  // (gw+16384)&3 == gw&3
    const int   s     = lane & 7;                // epilogue output selector
    float bias = 0.f, alpha = 0.f;
    if (s < 6) {
        alpha = (s == 0) ? apre : (s == 1) ? apost : ares;
        bias  = (s == 0) ? b_pre[n]
              : (s == 1) ? b_post[n]
                         : b_res[(s - 2) * 4 + n];
    }

    __syncthreads();

    // packed accumulators: [0]=even cols, [1]=odd cols; summed pre-reduction
    f32x2 sa = {0.f, 0.f}, sb = {0.f, 0.f};
    f32x2 pa0 = {0.f,0.f}, pa1 = {0.f,0.f}, pa2 = {0.f,0.f},
          pa3 = {0.f,0.f}, pa4 = {0.f,0.f}, pa5 = {0.f,0.f};
    f32x2 pb0 = {0.f,0.f}, pb1 = {0.f,0.f}, pb2 = {0.f,0.f},
          pb3 = {0.f,0.f}, pb4 = {0.f,0.f}, pb5 = {0.f,0.f};

#pragma unroll
    for (int chunk = 0; chunk < 2; ++chunk) {
        if (chunk == 1) {                        // chunk-1 loads (TLP hides latency)
            const float4* ra = xf4 + (size_t)r0 * 512 + 256;
            const float4* rb = xf4 + (size_t)r1 * 512 + 256;
#pragma unroll
            for (int j = 0; j < 4; ++j) {
                xa[j] = ra[j * 64 + lane];
                xb[j] = rb[j * 64 + lane];
            }
        }
#pragma unroll
        for (int j = 0; j < 4; ++j) {
            const float4 a = xa[j];
            const float4 b = xb[j];
            const f32x2 a01 = mk2(a.x, a.y), a23 = mk2(a.z, a.w);
            const f32x2 b01 = mk2(b.x, b.y), b23 = mk2(b.z, b.w);
            const float* tb = s_wt + chunk * 1024 + j * 256 + lane * 4;
            PKFMA(sa, a01, a01); PKFMA(sa, a23, a23);
            PKFMA(sb, b01, b01); PKFMA(sb, b23, b23);
            float4 t;
            f32x2 t01, t23;
            t = *(const float4*)(tb + 0 * DIM);
            t01 = mk2(t.x, t.y); t23 = mk2(t.z, t.w);
            PKFMA(pa0, t01, a01); PKFMA(pa0, t23, a23);
            PKFMA(pb0, t01, b01); PKFMA(pb0, t23, b23);
            t = *(const float4*)(tb + 1 * DIM);
            t01 = mk2(t.x, t.y); t23 = mk2(t.z, t.w);
            PKFMA(pa1, t01, a01); PKFMA(pa1, t23, a23);
            PKFMA(pb1, t01, b01); PKFMA(pb1, t23, b23);
            t = *(const float4*)(tb + 2 * DIM);
            t01 = mk2(t.x, t.y); t23 = mk2(t.z, t.w);
            PKFMA(pa2, t01, a01); PKFMA(pa2, t23, a23);
            PKFMA(pb2, t01, b01); PKFMA(pb2, t23, b23);
            t = *(const float4*)(tb + 3 * DIM);
            t01 = mk2(t.x, t.y); t23 = mk2(t.z, t.w);
            PKFMA(pa3, t01, a01); PKFMA(pa3, t23, a23);
            PKFMA(pb3, t01, b01); PKFMA(pb3, t23, b23);
            t = *(const float4*)(tb + 4 * DIM);
            t01 = mk2(t.x, t.y); t23 = mk2(t.z, t.w);
            PKFMA(pa4, t01, a01); PKFMA(pa4, t23, a23);
            PKFMA(pb4, t01, b01); PKFMA(pb4, t23, b23);
            t = *(const float4*)(tb + 5 * DIM);
            t01 = mk2(t.x, t.y); t23 = mk2(t.z, t.w);
            PKFMA(pa5, t01, a01); PKFMA(pa5, t23, a23);
            PKFMA(pb5, t01, b01); PKFMA(pb5, t23, b23);
        }
    }

    // horizontal add of packed halves, then 14 wave sums (DPP + 2 shuffles)
    float ssa = sa[0] + sa[1], ssb = sb[0] + sb[1];
    float da0 = pa0[0] + pa0[1], da1 = pa1[0] + pa1[1], da2 = pa2[0] + pa2[1];
    float da3 = pa3[0] + pa3[1], da4 = pa4[0] + pa4[1], da5 = pa5[0] + pa5[1];
    float db0 = pb0[0] + pb0[1], db1 = pb1[0] + pb1[1], db2 = pb2[0] + pb2[1];
    float db3 = pb3[0] + pb3[1], db4 = pb4[0] + pb4[1], db5 = pb5[0] + pb5[1];

    WAVE_SUM(ssa); WAVE_SUM(ssb);
    WAVE_SUM(da0); WAVE_SUM(da1); WAVE_SUM(da2);
    WAVE_SUM(da3); WAVE_SUM(da4); WAVE_SUM(da5);
    WAVE_SUM(db0); WAVE_SUM(db1); WAVE_SUM(db2);
    WAVE_SUM(db3); WAVE_SUM(db4); WAVE_SUM(db5);

    // ---- epilogue: lanes 0..5 write row r0, lanes 8..13 write row r1 ----
    const bool rowB = lane >= 8;
    if (s < 6 && lane < 14) {
        const float ss = rowB ? ssb : ssa;
        const float c0 = rowB ? db0 : da0;
        const float c1 = rowB ? db1 : da1;
        const float c2 = rowB ? db2 : da2;
        const float c3 = rowB ? db3 : da3;
        const float c4 = rowB ? db4 : da4;
        const float c5 = rowB ? db5 : da5;
        const float dv = (s == 0) ? c0 : (s == 1) ? c1 : (s == 2) ? c2
                       : (s == 3) ? c3 : (s == 4) ? c4 : c5;
        const int   r  = rowB ? r1 : r0;
        const float rstd = rsqrtf(ss * (1.0f / DIM) + EPS_RMS);
        const float val  = alpha * fast_tanh(dv * rstd) + bias;
        int addr;
        if (s == 0)      addr = r;
        else if (s == 1) addr = NROWS + r;
        else             addr = 2 * NROWS + (r >> 2) * 16 + (s - 2) * 4 + n;
        out[addr] = val;
    }
}

extern "C" void kernel_launch(void* const* d_in, const int* in_sizes, int n_in,
                              void* d_out, int out_size, void* d_ws, size_t ws_size,
                              hipStream_t stream) {
    const float* x          = (const float*)d_in[0];
    const float* rms_weight = (const float*)d_in[1];
    const float* alpha_pre  = (const float*)d_in[2];
    const float* alpha_post = (const float*)d_in[3];
    const float* alpha_res  = (const float*)d_in[4];
    const float* theta_pre  = (const float*)d_in[5];
    const float* theta_post = (const float*)d_in[6];
    const float* theta_res  = (const float*)d_in[7];
    const float* b_pre      = (const float*)d_in[8];
    const float* b_post     = (const float*)d_in[9];
    const float* b_res      = (const float*)d_in[10];
    float* out = (float*)d_out;

    dim3 grid(GRIDN);
    dim3 block(BLK);
    hipLaunchKernelGGL(hcmaps_kernel, grid, block, 0, stream,
                       x, rms_weight, alpha_pre, alpha_post, alpha_res,
                       theta_pre, theta_post, theta_res,
                       b_pre, b_post, b_res, out);
}

// Round 8
// 46.021 us; speedup vs baseline: 1.5499x; 1.0375x over previous
//
#include <hip/hip_runtime.h>
#include <math.h>

// B=2,T=4096,N=4,DIM=2048 -> 32768 rows of 2048 f32 (256 MiB in, 768 KiB out)
// out = H_pre[32768] ++ H_post[32768] ++ H_res[B,T,4,4] (131072), f32
//
// Fusion: dot(theta, x_tilde) = rstd * sum_c (theta[c]*w[c]) * x[c]
// -> single pass over x: sum(x^2) + 6 folded dots, then tanh epilogue.
//
// FINAL (round-5 structure, reverted after round-7 A/B):
//   - one wave computes TWO rows (gw, gw+16384): each ds_read_b128 of w*theta
//     feeds both rows' FMAs -> theta LDS traffic halved (48 -> 24 b128/row)
//   - x processed in two 1024-col chunks: only 32 VGPR of x live at a time
//     (rounds 2/3: bigger register buffers spill -> 160+ MB scratch traffic;
//      round 6: 64 VGPR of x crosses the VGPR-64 occupancy cliff -> 71us)
//   - wave reduction: 4x DPP row_ror adds (VALU) + 2 shuffles per chain
//     (round 4->5: ds_bpermute butterfly was the DS-pipe co-limiter)
//   - 1024-thread blocks, 48 KiB LDS, ~80 VGPR -> ~24 waves/CU resident
//   - round-7 A/B: v_pk_fma_f32 (half the VALU work) changed nothing ->
//     memory-path-bound at 5.77 TB/s = 92% of measured 6.29 TB/s ceiling
#define DIM     2048
#define NROWS   32768
#define EPS_RMS 1e-6f
#define NTH     6
#define BLK     1024
#define GRIDN   1024     // 16384 waves; each owns rows gw and gw+16384

__device__ __forceinline__ float fast_tanh(float x) {
    // tanh(x) = 1 - 2/(exp(2x)+1); ~1e-7 rel err, exact at +/-inf
    return 1.0f - 2.0f / (__expf(2.0f * x) + 1.0f);
}

#define DOT4(t, a) ((t).x*(a).x + (t).y*(a).y + (t).z*(a).z + (t).w*(a).w)

// v += row_ror:<k>(v)  (within 16-lane DPP rows; VALU pipe, no DS traffic)
#define ROR_ADD(v, CTRL)                                                      \
    do {                                                                      \
        int _iv = __float_as_int(v);                                          \
        int _r  = __builtin_amdgcn_update_dpp(_iv, _iv, (CTRL), 0xF, 0xF, false); \
        (v) += __int_as_float(_r);                                            \
    } while (0)

// full 64-lane sum, result broadcast to all lanes:
// 4 DPP rotate-adds (lanes hold 16-group sum) + xor16 + xor32
#define WAVE_SUM(v)                                                           \
    do {                                                                      \
        ROR_ADD(v, 0x121);  /* row_ror:1 */                                   \
        ROR_ADD(v, 0x122);  /* row_ror:2 */                                   \
        ROR_ADD(v, 0x124);  /* row_ror:4 */                                   \
        ROR_ADD(v, 0x128);  /* row_ror:8 */                                   \
        (v) += __shfl_xor((v), 16);                                           \
        (v) += __shfl_xor((v), 32);                                           \
    } while (0)

__global__ __launch_bounds__(BLK, 4) void hcmaps_kernel(
    const float* __restrict__ x,
    const float* __restrict__ w,
    const float* __restrict__ alpha_pre_p,
    const float* __restrict__ alpha_post_p,
    const float* __restrict__ alpha_res_p,
    const float* __restrict__ theta_pre,
    const float* __restrict__ theta_post,
    const float* __restrict__ theta_res,   // [4, DIM]
    const float* __restrict__ b_pre,       // [4]
    const float* __restrict__ b_post,      // [4]
    const float* __restrict__ b_res,       // [16] = [i][n]
    float* __restrict__ out)
{
    __shared__ float s_wt[NTH * DIM];      // 48 KiB: w*theta, 6 vectors

    const int tid  = threadIdx.x;
    const int lane = tid & 63;
    const int wid  = tid >> 6;
    const int gw   = blockIdx.x * 16 + wid;      // 0..16383
    const int r0   = gw;
    const int r1   = gw + 16384;

    const float4* __restrict__ xf4 = (const float4*)x;

    // ---- issue chunk-0 loads for BOTH rows first (hide under theta fill) ----
    float4 xa[4], xb[4];
    {
        const float4* ra = xf4 + (size_t)r0 * 512;
        const float4* rb = xf4 + (size_t)r1 * 512;
#pragma unroll
        for (int j = 0; j < 4; ++j) {
            xa[j] = ra[j * 64 + lane];
            xb[j] = rb[j * 64 + lane];
        }
    }

    // ---- fold w*theta into LDS (3 float4 per thread) ----
#pragma unroll
    for (int it = 0; it < 3; ++it) {
        const int q  = tid + it * BLK;           // 0..3071
        const int v  = q >> 9;                   // theta index 0..5
        const int cf = q & 511;                  // float4 col
        const float* tb = (v == 0) ? theta_pre
                        : (v == 1) ? theta_post
                                   : (theta_res + (v - 2) * DIM);
        const float4 wv = ((const float4*)w)[cf];
        const float4 t4 = ((const float4*)tb)[cf];
        ((float4*)s_wt)[q] =
            make_float4(wv.x * t4.x, wv.y * t4.y, wv.z * t4.z, wv.w * t4.w);
    }

    const float apre  = alpha_pre_p[0];
    const float apost = alpha_post_p[0];
    const float ares  = alpha_res_p[0];
    const int   n     = gw & 3;                  // (gw+16384)&3 == gw&3
    // per-lane epilogue constants: s = lane&7 selects output kind
    const int   s     = lane & 7;
    float bias = 0.f, alpha = 0.f;
    if (s < 6) {
        alpha = (s == 0) ? apre : (s == 1) ? apost : ares;
        bias  = (s == 0) ? b_pre[n]
              : (s == 1) ? b_post[n]
                         : b_res[(s - 2) * 4 + n];
    }

    __syncthreads();

    float ssa = 0.f, ssb = 0.f;
    float da0 = 0.f, da1 = 0.f, da2 = 0.f, da3 = 0.f, da4 = 0.f, da5 = 0.f;
    float db0 = 0.f, db1 = 0.f, db2 = 0.f, db3 = 0.f, db4 = 0.f, db5 = 0.f;

#pragma unroll
    for (int chunk = 0; chunk < 2; ++chunk) {
        if (chunk == 1) {                        // chunk-1 loads (TLP hides latency)
            const float4* ra = xf4 + (size_t)r0 * 512 + 256;
            const float4* rb = xf4 + (size_t)r1 * 512 + 256;
#pragma unroll
            for (int j = 0; j < 4; ++j) {
                xa[j] = ra[j * 64 + lane];
                xb[j] = rb[j * 64 + lane];
            }
        }
#pragma unroll
        for (int j = 0; j < 4; ++j) {
            const float4 a = xa[j];
            const float4 b = xb[j];
            const float* tb = s_wt + chunk * 1024 + j * 256 + lane * 4;
            ssa += DOT4(a, a);
            ssb += DOT4(b, b);
            float4 t;
            t = *(const float4*)(tb + 0 * DIM); da0 += DOT4(t, a); db0 += DOT4(t, b);
            t = *(const float4*)(tb + 1 * DIM); da1 += DOT4(t, a); db1 += DOT4(t, b);
            t = *(const float4*)(tb + 2 * DIM); da2 += DOT4(t, a); db2 += DOT4(t, b);
            t = *(const float4*)(tb + 3 * DIM); da3 += DOT4(t, a); db3 += DOT4(t, b);
            t = *(const float4*)(tb + 4 * DIM); da4 += DOT4(t, a); db4 += DOT4(t, b);
            t = *(const float4*)(tb + 5 * DIM); da5 += DOT4(t, a); db5 += DOT4(t, b);
        }
    }

    // ---- 14 wave sums: DPP rotates (VALU) + 2 shuffles each ----
    WAVE_SUM(ssa); WAVE_SUM(ssb);
    WAVE_SUM(da0); WAVE_SUM(da1); WAVE_SUM(da2);
    WAVE_SUM(da3); WAVE_SUM(da4); WAVE_SUM(da5);
    WAVE_SUM(db0); WAVE_SUM(db1); WAVE_SUM(db2);
    WAVE_SUM(db3); WAVE_SUM(db4); WAVE_SUM(db5);

    // ---- epilogue: lanes 0..5 write row r0, lanes 8..13 write row r1 ----
    const bool rowB = lane >= 8;
    if (s < 6 && lane < 14) {
        const float ss = rowB ? ssb : ssa;
        const float c0 = rowB ? db0 : da0;
        const float c1 = rowB ? db1 : da1;
        const float c2 = rowB ? db2 : da2;
        const float c3 = rowB ? db3 : da3;
        const float c4 = rowB ? db4 : da4;
        const float c5 = rowB ? db5 : da5;
        const float dv = (s == 0) ? c0 : (s == 1) ? c1 : (s == 2) ? c2
                       : (s == 3) ? c3 : (s == 4) ? c4 : c5;
        const int   r  = rowB ? r1 : r0;
        const float rstd = rsqrtf(ss * (1.0f / DIM) + EPS_RMS);
        const float val  = alpha * fast_tanh(dv * rstd) + bias;
        int addr;
        if (s == 0)      addr = r;
        else if (s == 1) addr = NROWS + r;
        else             addr = 2 * NROWS + (r >> 2) * 16 + (s - 2) * 4 + n;
        out[addr] = val;
    }
}

extern "C" void kernel_launch(void* const* d_in, const int* in_sizes, int n_in,
                              void* d_out, int out_size, void* d_ws, size_t ws_size,
                              hipStream_t stream) {
    const float* x          = (const float*)d_in[0];
    const float* rms_weight = (const float*)d_in[1];
    const float* alpha_pre  = (const float*)d_in[2];
    const float* alpha_post = (const float*)d_in[3];
    const float* alpha_res  = (const float*)d_in[4];
    const float* theta_pre  = (const float*)d_in[5];
    const float* theta_post = (const float*)d_in[6];
    const float* theta_res  = (const float*)d_in[7];
    const float* b_pre      = (const float*)d_in[8];
    const float* b_post     = (const float*)d_in[9];
    const float* b_res      = (const float*)d_in[10];
    float* out = (float*)d_out;

    dim3 grid(GRIDN);
    dim3 block(BLK);
    hipLaunchKernelGGL(hcmaps_kernel, grid, block, 0, stream,
                       x, rms_weight, alpha_pre, alpha_post, alpha_res,
                       theta_pre, theta_post, theta_res,
                       b_pre, b_post, b_res, out);
}